// Round 2
// baseline (4419.597 us; speedup 1.0000x reference)
//
#include <hip/hip_runtime.h>

#define T_STEPS 1024
#define BATCH   64
#define NDIM    256
#define HID     256
#define G4      1024   // 4*H

// log2(e) folded into the weights so gates use native v_exp_f32 (exp2):
//   f,i,o columns scaled by L2E  -> sigm(z)  = 1/(1+exp2(-acc))
//   g column scaled by 2*L2E     -> tanh(z)  = 2/(1+exp2(-acc)) - 1
#define L2E  1.4426950408889634f
#define L2E2 2.8853900817779268f

typedef short bf16x8 __attribute__((ext_vector_type(8)));
typedef float f32x4  __attribute__((ext_vector_type(4)));
typedef unsigned short u16;

#define XW_ELEMS ((size_t)2 * T_STEPS * BATCH * G4)   // 134217728 u16 (256 MiB)
#define UT_ELEMS ((size_t)2 * 4 * 65536)              // 524288 u16 (1 MiB)

__device__ __forceinline__ float b2f(u16 v) {
  union { unsigned u; float f; } c; c.u = ((unsigned)v) << 16; return c.f;
}
__device__ __forceinline__ u16 f2b(float f) {
  union { float f; unsigned u; } c; c.f = f;
  unsigned u = c.u;
  u += 0x7fffu + ((u >> 16) & 1u);   // round-to-nearest-even
  return (u16)(u >> 16);
}

// ---------------------------------------------------------------------------
// build_ut: pre-transpose U (f32) into bf16 MFMA B-fragment order, with the
// exp2 gate scaling folded in.
// UT elem idx: ((d*4+g)*65536) + ((w*8+kf)*64 + lane)*8 + j
// ---------------------------------------------------------------------------
__global__ __launch_bounds__(1024) void build_ut(
    const float* __restrict__ U0, const float* __restrict__ U1,
    u16* __restrict__ UT)
{
  const int d = blockIdx.x >> 2;
  const int g = blockIdx.x & 3;
  const float sc = (g == 1) ? L2E2 : L2E;
  const float* __restrict__ U = d ? U1 : U0;
  const int w = threadIdx.x >> 6, lane = threadIdx.x & 63;
  const int q = lane >> 4, c15 = lane & 15;
  u16* dst = UT + ((size_t)d * 4 + g) * 65536;
  #pragma unroll
  for (int kf = 0; kf < 8; ++kf) {
    bf16x8 v;
    #pragma unroll
    for (int j = 0; j < 8; ++j)
      v[j] = (short)f2b(sc * U[(size_t)(kf * 32 + q * 8 + j) * G4 + g * 256 + w * 16 + c15]);
    ((bf16x8*)dst)[((w * 8 + kf) << 6) + lane] = v;
  }
}

// ---------------------------------------------------------------------------
// Phase 1: xw = (x @ W_d + b_d) * gate_scale, bf16, scan-consumption order:
//   elem idx = (((d*T + t)*4 + bt)*1024 + tid)*16 + gate*4 + r
// 64-col N-tiles (uf = 128 VGPRs), t-chunk 32 -> grid 1024 blocks, 2 blk/CU.
// ---------------------------------------------------------------------------
__global__ __launch_bounds__(256, 2) void xw_gemm(
    const float* __restrict__ x,
    const float* __restrict__ W0, const float* __restrict__ W1,
    const float* __restrict__ b0, const float* __restrict__ b1,
    u16* __restrict__ xw)
{
  const int d  = blockIdx.y >> 4;
  const int n0 = (blockIdx.y & 15) * 64;
  const int t0 = blockIdx.x * 32;
  const float* __restrict__ W    = d ? W1 : W0;
  const float* __restrict__ bias = d ? b1 : b0;
  const int lane = threadIdx.x & 63;
  const int wv   = threadIdx.x >> 6;
  const int q    = lane >> 4;
  const int c15  = lane & 15;

  bf16x8 uf[4][8];
  float bc[4];
  #pragma unroll
  for (int ct = 0; ct < 4; ++ct) {
    const int col = n0 + ct * 16 + c15;
    const float sc = (((n0 + ct * 16) >> 8) == 1) ? L2E2 : L2E;
    #pragma unroll
    for (int kf = 0; kf < 8; ++kf) {
      #pragma unroll
      for (int j = 0; j < 8; ++j)
        uf[ct][kf][j] = (short)f2b(sc * W[(size_t)(kf * 32 + q * 8 + j) * G4 + col]);
    }
    bc[ct] = sc * bias[col];
  }

  __shared__ __align__(16) u16 Alds[64 * 256];

  for (int t = t0; t < t0 + 32; ++t) {
    __syncthreads();
    const float* xt = x + (size_t)t * BATCH * NDIM;
    #pragma unroll
    for (int i = 0; i < 8; ++i) {
      int g = (int)threadIdx.x + 256 * i;
      int r = g >> 5, c = g & 31;
      const float* src = xt + r * 256 + c * 8;
      bf16x8 v;
      #pragma unroll
      for (int j = 0; j < 8; ++j) v[j] = (short)f2b(src[j]);
      int cs = (c & 16) | ((c ^ (r & 15)) & 15);
      ((bf16x8*)Alds)[r * 32 + cs] = v;
    }
    __syncthreads();

    bf16x8 af[8];
    const int arow = wv * 16 + c15;
    #pragma unroll
    for (int kf = 0; kf < 8; ++kf) {
      int c = kf * 4 + q;
      int cs = (c & 16) | ((c ^ c15) & 15);
      af[kf] = ((const bf16x8*)Alds)[arow * 32 + cs];
    }

    f32x4 acc[4];
    #pragma unroll
    for (int ct = 0; ct < 4; ++ct) acc[ct] = (f32x4){0.f, 0.f, 0.f, 0.f};
    #pragma unroll
    for (int kf = 0; kf < 8; ++kf) {
      #pragma unroll
      for (int ct = 0; ct < 4; ++ct)
        acc[ct] = __builtin_amdgcn_mfma_f32_16x16x32_bf16(af[kf], uf[ct][kf], acc[ct], 0, 0, 0);
    }

    u16* dst = xw + (((size_t)d * T_STEPS + t) * 4 + wv) * 16384;
    #pragma unroll
    for (int ct = 0; ct < 4; ++ct) {
      int ncol = n0 + ct * 16;
      int g2 = ncol >> 8, w2 = (ncol >> 4) & 15;
      union { u16 s[4]; uint2 v; } pk;
      #pragma unroll
      for (int r = 0; r < 4; ++r) pk.s[r] = f2b(acc[ct][r] + bc[ct]);
      *(uint2*)(dst + (size_t)(w2 * 64 + q * 16 + c15) * 16 + g2 * 4) = pk.v;
    }
  }
}

// ---------------------------------------------------------------------------
// Phase 2 (fast): grid 8 = (d, bt). 16 waves; wave w owns h-cols [w*16,+16).
// U by gate: f,g in 64 VGPRs; i in 128 KB LDS; o streamed from L2 (rolling
// 3-slot buffer, prefetch distance 3 kf-iterations, persistent across the
// step boundary). acc seeded with xw pre-activations (prefetched one step
// ahead). Gate math in exp2 domain (weights pre-scaled by log2e / 2log2e)
// with combined-reciprocal algebra: 7 TRANS ops per output instead of 10.
// Dynamic LDS 147456 B: [0,16384) h ping-pong (8 KB each), [16384,..) U_i.
// ---------------------------------------------------------------------------
__global__ __launch_bounds__(1024) void lstm_scan_fast(
    const u16* __restrict__ xw, const u16* __restrict__ UT,
    float* __restrict__ out)
{
  extern __shared__ __align__(16) u16 dynlds[];
  const int d  = blockIdx.x >> 2;
  const int bt = blockIdx.x & 3;
  const int tid  = threadIdx.x;
  const int w    = tid >> 6;
  const int lane = tid & 63;
  const int q    = lane >> 4;
  const int c15  = lane & 15;

  const u16* __restrict__ UTd = UT + (size_t)d * 4 * 65536;

  // persistent register fragments for gates f(0), g(1)
  bf16x8 uf0[8], uf1[8];
  const bf16x8* UTf = (const bf16x8*)UTd;
  #pragma unroll
  for (int kf = 0; kf < 8; ++kf) {
    uf0[kf] = UTf[       ((w * 8 + kf) << 6) + lane];
    uf1[kf] = UTf[8192 + ((w * 8 + kf) << 6) + lane];
  }

  // stage i-gate into LDS + zero both h buffers
  {
    const int4* src = (const int4*)(UTd + 2 * 65536);
    int4* dstl = (int4*)(dynlds + 8192);
    for (int i = tid; i < 8192; i += 1024) dstl[i] = src[i];
    for (int i = tid; i < 8192; i += 1024) dynlds[i] = 0;
  }

  const int4* __restrict__ Uo4 = (const int4*)(UTd + 3 * 65536);
  const int obase = (w << 9) | lane;
  const char* uib_base = (const char*)(dynlds + 8192) + (size_t)obase * 16;  // +kf*1024 imm

  // precomputed LDS byte offsets; h buffer selected by XOR 8192
  int afo[8];
  #pragma unroll
  for (int kf = 0; kf < 8; ++kf) {
    int cc = kf * 4 + q;
    int cs = (cc & 16) | ((cc ^ c15) & 15);
    afo[kf] = (c15 * 32 + cs) * 16;
  }
  const int colv = w * 16 + c15;
  int hwo[4];
  #pragma unroll
  for (int r = 0; r < 4; ++r) {
    int row = q * 4 + r;
    int cch = colv >> 3;
    int cs = (cch & 16) | ((cch ^ row) & 15);
    hwo[r] = ((row * 32 + cs) * 8 + (colv & 7)) * 2;
  }

  float cst[4] = {0.f, 0.f, 0.f, 0.f};
  __syncthreads();

  const int rowbase = bt * 16;
  const size_t hlast_base = (size_t)T_STEPS * BATCH * (2 * HID) + (size_t)d * BATCH * HID;
  const int t_first = d ? (T_STEPS - 1) : 0;

  // xw walking pointer; prefetch step 0
  const long xw_stride = d ? -(long)(4 * 16384) : (long)(4 * 16384);
  const u16* xwp = xw + (((size_t)d * T_STEPS + t_first) * 4 + bt) * 16384 + (size_t)tid * 16;
  union I4x2 { int4 v[2]; u16 s[16]; };
  I4x2 xn;
  xn.v[0] = ((const int4*)xwp)[0];
  xn.v[1] = ((const int4*)xwp)[1];
  xwp += xw_stride;

  // o-gate rolling L2 stream: 3 slots covering kf, kf+1, kf+2 at step start
  int4 ofr[3];
  ofr[0] = Uo4[obase];
  ofr[1] = Uo4[obase + 64];
  ofr[2] = Uo4[obase + 128];

  // i-gate first fragment preloaded (constant data, race-free across steps)
  bf16x8 uib[2];
  uib[0] = *(const bf16x8*)(uib_base);

  // out walking pointer
  float* outp = out + (size_t)(t_first * BATCH + rowbase + q * 4) * (2 * HID)
              + (size_t)d * HID + colv;
  const long out_stride = d ? -(long)(BATCH * 2 * HID) : (long)(BATCH * 2 * HID);

  int curoff = 0;
  for (int it = 0; it < T_STEPS; ++it) {
    // seed accumulators with current step's pre-activations (already scaled)
    f32x4 acc0 = { b2f(xn.s[0]),  b2f(xn.s[1]),  b2f(xn.s[2]),  b2f(xn.s[3])  };
    f32x4 acc1 = { b2f(xn.s[4]),  b2f(xn.s[5]),  b2f(xn.s[6]),  b2f(xn.s[7])  };
    f32x4 acc2 = { b2f(xn.s[8]),  b2f(xn.s[9]),  b2f(xn.s[10]), b2f(xn.s[11]) };
    f32x4 acc3 = { b2f(xn.s[12]), b2f(xn.s[13]), b2f(xn.s[14]), b2f(xn.s[15]) };

    // prefetch next step's xw (hidden under this step's MFMA+gates)
    if (it + 1 < T_STEPS) {
      xn.v[0] = ((const int4*)xwp)[0];
      xn.v[1] = ((const int4*)xwp)[1];
      xwp += xw_stride;
    }

    const char* hcb = (const char*)dynlds + curoff;
    bf16x8 afb[2];
    afb[0] = *(const bf16x8*)(hcb + afo[0]);
    #pragma unroll
    for (int kf = 0; kf < 8; ++kf) {
      if (kf < 7) {
        afb[(kf + 1) & 1] = *(const bf16x8*)(hcb + afo[kf + 1]);
        uib[(kf + 1) & 1] = *(const bf16x8*)(uib_base + (kf + 1) * 1024);
      }
      union { int4 v; bf16x8 b; } oc; oc.v = ofr[kf % 3];
      // prefetch kf+3 into the slot just freed: distance 3 kf-iterations
      if (kf < 5) ofr[kf % 3] = Uo4[obase + ((kf + 3) << 6)];
      bf16x8 af = afb[kf & 1];
      acc0 = __builtin_amdgcn_mfma_f32_16x16x32_bf16(af, uf0[kf],     acc0, 0, 0, 0);
      acc1 = __builtin_amdgcn_mfma_f32_16x16x32_bf16(af, uf1[kf],     acc1, 0, 0, 0);
      acc2 = __builtin_amdgcn_mfma_f32_16x16x32_bf16(af, uib[kf & 1], acc2, 0, 0, 0);
      acc3 = __builtin_amdgcn_mfma_f32_16x16x32_bf16(af, oc.b,        acc3, 0, 0, 0);
    }
    // refill all 3 o-stream slots for NEXT step; latency hides under the gates
    ofr[0] = Uo4[obase];
    ofr[1] = Uo4[obase + 64];
    ofr[2] = Uo4[obase + 128];

    // gates: exp2 domain, combined reciprocals (5 exp + 2 rcp per r)
    float hv[4];
    #pragma unroll
    for (int r = 0; r < 4; ++r) {
      float ef = __builtin_amdgcn_exp2f(-acc0[r]);
      float eg = __builtin_amdgcn_exp2f(-acc1[r]);
      float ei = __builtin_amdgcn_exp2f(-acc2[r]);
      float eo = __builtin_amdgcn_exp2f(-acc3[r]);
      float A = 1.0f + ef, B = 1.0f + eg, C = 1.0f + ei, D = 1.0f - eg;
      float BC  = B * C;
      float num = cst[r] * BC + D * A;
      float cn  = num * __builtin_amdgcn_rcpf(A * BC);
      cst[r] = cn;
      float ec = __builtin_amdgcn_exp2f(fminf(-L2E2 * cn, 30.0f));
      float E = 1.0f + eo, F = 1.0f + ec, G = 1.0f - ec;
      hv[r] = G * __builtin_amdgcn_rcpf(E * F);   // = sigm(o) * tanh(c)
    }
    unsigned p01, p23;
    asm("v_cvt_pk_bf16_f32 %0, %1, %2" : "=v"(p01) : "v"(hv[0]), "v"(hv[1]));
    asm("v_cvt_pk_bf16_f32 %0, %1, %2" : "=v"(p23) : "v"(hv[2]), "v"(hv[3]));
    u16 hb[4] = { (u16)p01, (u16)(p01 >> 16), (u16)p23, (u16)(p23 >> 16) };

    const int nxtoff = curoff ^ 8192;
    char* hwp = (char*)dynlds + nxtoff;
    #pragma unroll
    for (int r = 0; r < 4; ++r) {
      *(u16*)(hwp + hwo[r]) = hb[r];
      outp[r * (2 * HID)] = hv[r];          // imm offsets 0/2048/4096/6144 B
    }
    outp += out_stride;
    if (it == T_STEPS - 1) {
      #pragma unroll
      for (int r = 0; r < 4; ++r)
        out[hlast_base + (size_t)(rowbase + q * 4 + r) * HID + colv] = hv[r];
    }
    curoff = nxtoff;
    // hoist next step's constant U_i fragment above the barrier
    uib[0] = *(const bf16x8*)(uib_base);
    __syncthreads();
  }
}

// ---------------------------------------------------------------------------
// Phase 2 (safe fallback if ws too small for UT): correct but slow.
// Consumes the SCALED xw, so it applies the same scaling to U and the same
// exp2-domain gate math.
// ---------------------------------------------------------------------------
__global__ __launch_bounds__(1024) void lstm_scan_safe(
    const u16* __restrict__ xw,
    const float* __restrict__ U0, const float* __restrict__ U1,
    float* __restrict__ out)
{
  const int d  = blockIdx.x >> 2;
  const int bt = blockIdx.x & 3;
  const int tid  = threadIdx.x;
  const int w    = tid >> 6;
  const int lane = tid & 63;
  const int q    = lane >> 4;
  const int c15  = lane & 15;
  const float* __restrict__ U = d ? U1 : U0;

  bf16x8 uf[4][8];
  #pragma unroll
  for (int g = 0; g < 4; ++g) {
    const int col2 = g * 256 + w * 16 + c15;
    const float sc = (g == 1) ? L2E2 : L2E;
    #pragma unroll
    for (int kf = 0; kf < 8; ++kf) {
      #pragma unroll
      for (int j = 0; j < 8; ++j)
        uf[g][kf][j] = (short)f2b(sc * U[(size_t)(kf * 32 + q * 8 + j) * G4 + col2]);
    }
  }

  __shared__ __align__(16) u16 hbuf[2][16 * 256];
  for (int i = tid; i < 16 * 256; i += 1024) { hbuf[0][i] = 0; hbuf[1][i] = 0; }
  float cst[4] = {0.f, 0.f, 0.f, 0.f};
  __syncthreads();

  const int rowbase = bt * 16;
  const int col = w * 16 + c15;
  const size_t hlast_base = (size_t)T_STEPS * BATCH * (2 * HID) + (size_t)d * BATCH * HID;

  for (int it = 0; it < T_STEPS; ++it) {
    const int t = d ? (T_STEPS - 1 - it) : it;
    union { int4 v[2]; u16 s[16]; } xv;
    {
      const int4* xwt = (const int4*)(xw + ((((size_t)d * T_STEPS + t) * 4 + bt) * 1024 + tid) * 16);
      xv.v[0] = xwt[0]; xv.v[1] = xwt[1];
    }
    const int cur = it & 1;
    bf16x8 af[8];
    #pragma unroll
    for (int kf = 0; kf < 8; ++kf) {
      int cc = kf * 4 + q;
      int cs = (cc & 16) | ((cc ^ c15) & 15);
      af[kf] = ((const bf16x8*)hbuf[cur])[c15 * 32 + cs];
    }
    f32x4 acc[4];
    #pragma unroll
    for (int g = 0; g < 4; ++g) acc[g] = (f32x4){0.f, 0.f, 0.f, 0.f};
    #pragma unroll
    for (int kf = 0; kf < 8; ++kf)
      #pragma unroll
      for (int g = 0; g < 4; ++g)
        acc[g] = __builtin_amdgcn_mfma_f32_16x16x32_bf16(af[kf], uf[g][kf], acc[g], 0, 0, 0);

    u16 hb[4]; float hv[4];
    #pragma unroll
    for (int r = 0; r < 4; ++r) {
      float zf = acc[0][r] + b2f(xv.s[0 * 4 + r]);
      float zg = acc[1][r] + b2f(xv.s[1 * 4 + r]);
      float zi = acc[2][r] + b2f(xv.s[2 * 4 + r]);
      float zo = acc[3][r] + b2f(xv.s[3 * 4 + r]);
      float ef = __builtin_amdgcn_exp2f(-zf);
      float eg = __builtin_amdgcn_exp2f(-zg);
      float ei = __builtin_amdgcn_exp2f(-zi);
      float eo = __builtin_amdgcn_exp2f(-zo);
      float A = 1.0f + ef, B = 1.0f + eg, C = 1.0f + ei, D = 1.0f - eg;
      float BC  = B * C;
      float num = cst[r] * BC + D * A;
      float cn  = num * __builtin_amdgcn_rcpf(A * BC);
      cst[r] = cn;
      float ec = __builtin_amdgcn_exp2f(fminf(-L2E2 * cn, 30.0f));
      float E = 1.0f + eo, F = 1.0f + ec, G = 1.0f - ec;
      hv[r] = G * __builtin_amdgcn_rcpf(E * F);
      hb[r] = f2b(hv[r]);
    }
    const int nxt = cur ^ 1;
    #pragma unroll
    for (int r = 0; r < 4; ++r) {
      const int row = q * 4 + r;
      int cch = col >> 3;
      int cs = (cch & 16) | ((cch ^ row) & 15);
      hbuf[nxt][(row * 32 + cs) * 8 + (col & 7)] = hb[r];
      out[((size_t)t * BATCH + rowbase + row) * (2 * HID) + (size_t)d * HID + col] = hv[r];
    }
    if (it == T_STEPS - 1) {
      #pragma unroll
      for (int r = 0; r < 4; ++r)
        out[hlast_base + (size_t)(rowbase + q * 4 + r) * HID + col] = hv[r];
    }
    __syncthreads();
  }
}

extern "C" void kernel_launch(void* const* d_in, const int* in_sizes, int n_in,
                              void* d_out, int out_size, void* d_ws, size_t ws_size,
                              hipStream_t stream) {
  const float* x  = (const float*)d_in[0];
  const float* fW = (const float*)d_in[1];
  const float* fU = (const float*)d_in[2];
  const float* fb = (const float*)d_in[3];
  const float* bW = (const float*)d_in[4];
  const float* bU = (const float*)d_in[5];
  const float* bb = (const float*)d_in[6];
  u16*   xwbuf = (u16*)d_ws;
  u16*   UT    = (u16*)d_ws + XW_ELEMS;
  float* out   = (float*)d_out;

  const bool fast = ws_size >= (XW_ELEMS + UT_ELEMS) * sizeof(u16);

  dim3 g1(32, 32);
  xw_gemm<<<g1, 256, 0, stream>>>(x, fW, bW, fb, bb, xwbuf);
  if (fast) {
    build_ut<<<8, 1024, 0, stream>>>(fU, bU, UT);
    hipFuncSetAttribute((const void*)lstm_scan_fast,
                        hipFuncAttributeMaxDynamicSharedMemorySize, 147456);
    lstm_scan_fast<<<8, 1024, 147456, stream>>>(xwbuf, UT, out);
  } else {
    lstm_scan_safe<<<8, 1024, 0, stream>>>(xwbuf, fU, bU, out);
  }
}